// Round 8
// baseline (181.157 us; speedup 1.0000x reference)
//
#include <hip/hip_runtime.h>
#include <hip/hip_bf16.h>

// B=4, L=128, C=1024, D=512, fp32.
// out[b,l,c] = softmax_c( sum_d V[d]*tanh(wq[b,l,d] + uc[b,c,d]) )
// tanh(x) = 1 - 2/(e^{2x}+1);  e^{2(wq+uc)} = e^{2wq} * e^{2uc};
// softmax shift-invariance drops the constant sum(V):
//   align'[b,l,c] = sum_d (-2 V_d) * rcp(ewq[b,d,l]*euc[b,d,c] + 1)
// R8: PAIRED over d (1 rcp per 2 elems):
//   V0/(1+p0)+V1/(1+p1) = (V0*t1+V1*t0)/(t0*t1),  t=1+p
// -> 6 VALU + 1 trans per pair (trans was the binding pipe: 1/8 VALU rate).
//
// fused_align8: c-tile 128 (2 c/lane, b64 e-reads), l-tile 16 (4 l/wave via
//   q in chunk-prefetched REGISTERS from wave-uniform global b128 - no LDS,
//   no s_load), chunk 16 d double-buffered via global_load_lds w16.
//   LDS 16.5KB -> 4 blocks/CU; grid 1024 blocks; d-split 4 partials.

#define SCALE2 2.8853900817779268f  // 2*log2(e)

typedef _Float16 f16x8 __attribute__((ext_vector_type(8)));
typedef float f32x4 __attribute__((ext_vector_type(4)));

__device__ __forceinline__ void gload16(const void* g, void* l) {
    __builtin_amdgcn_global_load_lds(
        (const __attribute__((address_space(1))) void*)g,
        (__attribute__((address_space(3))) void*)l,
        16, 0, 0);
}

// ---------------------------------------------------------------------------
// GEMM + exp2 via fp16-split MFMA (unchanged from R6/R7, ~16us).
// ---------------------------------------------------------------------------
__global__ __launch_bounds__(256) void gemm_mfma(
    const float* __restrict__ hidden, const float* __restrict__ ctx,
    const float* __restrict__ Wmat, const float* __restrict__ Umat,
    const float* __restrict__ U_b,
    float* __restrict__ ewq_t, float* __restrict__ euc_t)
{
    __shared__ __align__(16) _Float16 Xh[2][64][40];
    __shared__ __align__(16) _Float16 Xl[2][64][40];
    __shared__ __align__(16) _Float16 Wh[2][64][40];
    __shared__ __align__(16) _Float16 Wl[2][64][40];

    const int tid  = threadIdx.x;
    const int lane = tid & 63;
    const int w    = tid >> 6;

    const float *X, *Wm, *bias;
    float* Ct;
    int m0, crow0, Mb, bshift;
    {
        int gb = blockIdx.x;
        if (gb < 64) {
            m0 = (gb & 7) * 64; crow0 = (gb >> 3) * 64;
            X = hidden; Wm = Wmat; bias = nullptr; Ct = ewq_t; Mb = 128; bshift = 7;
        } else {
            int g = gb - 64;
            m0 = (g & 7) * 64; crow0 = (g >> 3) * 64;
            X = ctx; Wm = Umat; bias = U_b; Ct = euc_t; Mb = 1024; bshift = 10;
        }
    }

    const int sr = tid >> 2;
    const int sk = (tid & 3) * 8;
    const float* xsrc = X  + (size_t)(crow0 + sr) * 512 + sk;
    const float* wsrc = Wm + (size_t)(m0    + sr) * 512 + sk;

    f32x4 acc[4];
#pragma unroll
    for (int t = 0; t < 4; ++t) acc[t] = (f32x4){0.f, 0.f, 0.f, 0.f};

    float xr[8], wr[8];
    {
        float4 a = *(const float4*)(xsrc);
        float4 b = *(const float4*)(xsrc + 4);
        float4 c = *(const float4*)(wsrc);
        float4 d = *(const float4*)(wsrc + 4);
        xr[0]=a.x; xr[1]=a.y; xr[2]=a.z; xr[3]=a.w; xr[4]=b.x; xr[5]=b.y; xr[6]=b.z; xr[7]=b.w;
        wr[0]=c.x; wr[1]=c.y; wr[2]=c.z; wr[3]=c.w; wr[4]=d.x; wr[5]=d.y; wr[6]=d.z; wr[7]=d.w;
        f16x8 xh, xl, wh, wl;
#pragma unroll
        for (int i = 0; i < 8; ++i) {
            xh[i] = (_Float16)xr[i]; xl[i] = (_Float16)(xr[i] - (float)xh[i]);
            wh[i] = (_Float16)wr[i]; wl[i] = (_Float16)(wr[i] - (float)wh[i]);
        }
        *(f16x8*)&Xh[0][sr][sk] = xh; *(f16x8*)&Xl[0][sr][sk] = xl;
        *(f16x8*)&Wh[0][sr][sk] = wh; *(f16x8*)&Wl[0][sr][sk] = wl;
    }

    const int fr = lane & 15;
    const int fk = (lane >> 4) * 8;
    const int mrow = w * 16 + fr;

    for (int kc = 0; kc < 16; ++kc) {
        if (kc < 15) {
            float4 a = *(const float4*)(xsrc + (kc + 1) * 32);
            float4 b = *(const float4*)(xsrc + (kc + 1) * 32 + 4);
            float4 c = *(const float4*)(wsrc + (kc + 1) * 32);
            float4 d = *(const float4*)(wsrc + (kc + 1) * 32 + 4);
            xr[0]=a.x; xr[1]=a.y; xr[2]=a.z; xr[3]=a.w; xr[4]=b.x; xr[5]=b.y; xr[6]=b.z; xr[7]=b.w;
            wr[0]=c.x; wr[1]=c.y; wr[2]=c.z; wr[3]=c.w; wr[4]=d.x; wr[5]=d.y; wr[6]=d.z; wr[7]=d.w;
        }
        __syncthreads();
        const int bu = kc & 1;
        const f16x8 ah = *(const f16x8*)&Wh[bu][mrow][fk];
        const f16x8 al = *(const f16x8*)&Wl[bu][mrow][fk];
#pragma unroll
        for (int t = 0; t < 4; ++t) {
            const f16x8 bh = *(const f16x8*)&Xh[bu][t * 16 + fr][fk];
            const f16x8 bl = *(const f16x8*)&Xl[bu][t * 16 + fr][fk];
            acc[t] = __builtin_amdgcn_mfma_f32_16x16x32_f16(ah, bh, acc[t], 0, 0, 0);
            acc[t] = __builtin_amdgcn_mfma_f32_16x16x32_f16(ah, bl, acc[t], 0, 0, 0);
            acc[t] = __builtin_amdgcn_mfma_f32_16x16x32_f16(al, bh, acc[t], 0, 0, 0);
        }
        if (kc < 15) {
            f16x8 xh, xl, wh, wl;
#pragma unroll
            for (int i = 0; i < 8; ++i) {
                xh[i] = (_Float16)xr[i]; xl[i] = (_Float16)(xr[i] - (float)xh[i]);
                wh[i] = (_Float16)wr[i]; wl[i] = (_Float16)(wr[i] - (float)wh[i]);
            }
            *(f16x8*)&Xh[bu ^ 1][sr][sk] = xh; *(f16x8*)&Xl[bu ^ 1][sr][sk] = xl;
            *(f16x8*)&Wh[bu ^ 1][sr][sk] = wh; *(f16x8*)&Wl[bu ^ 1][sr][sk] = wl;
        }
    }

    const int rbase = m0 + w * 16 + (lane >> 4) * 4;
    float bl4[4] = {0.f, 0.f, 0.f, 0.f};
    if (bias) {
        float4 t = *(const float4*)&bias[rbase];
        bl4[0] = t.x; bl4[1] = t.y; bl4[2] = t.z; bl4[3] = t.w;
    }
    const int bidx = crow0 >> bshift;
    const int cl0  = crow0 & (Mb - 1);
    float* obase = Ct + ((size_t)bidx * 512 + rbase) * Mb + cl0 + fr;
#pragma unroll
    for (int r = 0; r < 4; ++r)
#pragma unroll
        for (int t = 0; t < 4; ++t)
            obase[(size_t)r * Mb + t * 16] =
                __builtin_amdgcn_exp2f(SCALE2 * (acc[t][r] + bl4[r]));
}

// ---------------------------------------------------------------------------
// Fused align v8 (paired-rcp). Block = 128 c x 16 l x 128 d; 4 waves.
// Wave w owns l0+w*4..+3 (q via prefetched uniform global b128 -> regs).
// Lane owns c0+2*lane, +1 (b64 LDS e-reads). d in 8 chunks of 16,
// double-buffered via global_load_lds w16 (2 rows per instr).
// Grid (8, 8, 16): z = b*4+h; partial h -> p[h]; softmax3 sums.
// ---------------------------------------------------------------------------
__global__ __launch_bounds__(256) void fused_align8(
    const float* __restrict__ ewq_t,  // [4][512][128]
    const float* __restrict__ euc_t,  // [4][512][1024]
    const float* __restrict__ Vv,     // [512]
    float* __restrict__ p0, float* __restrict__ p1,
    float* __restrict__ p2, float* __restrict__ p3)
{
    __shared__ __align__(16) float uc_s[2][16][128];  // 16 KB
    __shared__ float2 v2_s[64];                       // 64 d-pairs

    const int tid  = threadIdx.x;
    const int lane = tid & 63;
    const int w    = __builtin_amdgcn_readfirstlane(tid >> 6);
    const int c0   = blockIdx.x * 128;   // 8
    const int l0   = blockIdx.y * 16;    // 8
    const int z    = blockIdx.z;         // 16
    const int b    = z >> 2, h = z & 3;
    const int d0   = h * 128;

    const float* ucb = euc_t + ((size_t)b * 512 + d0) * 1024 + c0;
    const float* wqb = ewq_t + ((size_t)b * 512 + d0) * 128 + l0 + w * 4;

    if (tid < 64)
        v2_s[tid] = make_float2(Vv[d0 + 2 * tid], Vv[d0 + 2 * tid + 1]);

    // stage 16 rows (chunk) of the 128-c slice; wave w does rows w*4..w*4+3
    // via two gload16 (each covers 2 rows: lanes 0-31 row r, 32-63 row r+1).
#define STAGE(buf, chunk)                                                     \
    {                                                                         \
        const float* s_ = ucb +                                               \
            (size_t)((chunk) * 16 + w * 4 + (lane >> 5)) * 1024 +             \
            (lane & 31) * 4;                                                  \
        gload16(s_,        &uc_s[buf][w * 4][0]);                             \
        gload16(s_ + 2048, &uc_s[buf][w * 4 + 2][0]);                         \
    }

#define QLOAD(Q, chunk)                                                       \
    {                                                                         \
        _Pragma("unroll")                                                     \
        for (int j_ = 0; j_ < 16; ++j_)                                       \
            Q[j_] = *(const float4*)(wqb + (size_t)((chunk) * 16 + j_) * 128);\
    }

    float acc[4][2];
#pragma unroll
    for (int i = 0; i < 4; ++i) { acc[i][0] = 0.f; acc[i][1] = 0.f; }

#define COMPUTE(buf, Q, ch)                                                   \
    {                                                                         \
        _Pragma("unroll")                                                     \
        for (int j = 0; j < 8; ++j) {                                         \
            const float2 e0 = *(const float2*)&uc_s[buf][2 * j][lane * 2];    \
            const float2 e1 = *(const float2*)&uc_s[buf][2 * j + 1][lane * 2];\
            const float2 vp = v2_s[(ch) * 8 + j];                             \
            const float4 q0 = Q[2 * j], q1 = Q[2 * j + 1];                    \
            const float q0a[4] = {q0.x, q0.y, q0.z, q0.w};                    \
            const float q1a[4] = {q1.x, q1.y, q1.z, q1.w};                    \
            const float e0a[2] = {e0.x, e0.y};                                \
            const float e1a[2] = {e1.x, e1.y};                                \
            _Pragma("unroll")                                                 \
            for (int i = 0; i < 4; ++i) {                                     \
                _Pragma("unroll")                                             \
                for (int k = 0; k < 2; ++k) {                                 \
                    const float t0 = fmaf(q0a[i], e0a[k], 1.0f);              \
                    const float t1 = fmaf(q1a[i], e1a[k], 1.0f);              \
                    const float den = t0 * t1;                                \
                    const float n = fmaf(vp.x, t1, vp.y * t0);                \
                    acc[i][k] = fmaf(n, __builtin_amdgcn_rcpf(den), acc[i][k]);\
                }                                                             \
            }                                                                 \
        }                                                                     \
    }

    float4 qa[16], qb[16];
    STAGE(0, 0);
    QLOAD(qa, 0);
    __syncthreads();

#pragma unroll
    for (int cc = 0; cc < 4; ++cc) {
        const int ch0 = cc * 2, ch1 = cc * 2 + 1;
        {   // even chunk: compute from buf0/qa, prefetch ch0+1 into buf1/qb
            STAGE(1, ch0 + 1);
            QLOAD(qb, ch0 + 1);
            COMPUTE(0, qa, ch0);
            __syncthreads();
        }
        {   // odd chunk: compute from buf1/qb, prefetch ch1+1 into buf0/qa
            if (ch1 < 7) {
                STAGE(0, ch1 + 1);
                QLOAD(qa, ch1 + 1);
            }
            COMPUTE(1, qb, ch1);
            __syncthreads();
        }
    }
#undef STAGE
#undef QLOAD
#undef COMPUTE

    float* pp = (h == 0) ? p0 : (h == 1) ? p1 : (h == 2) ? p2 : p3;
#pragma unroll
    for (int i = 0; i < 4; ++i) {
        float2 r;
        r.x = -2.0f * acc[i][0];
        r.y = -2.0f * acc[i][1];
        *(float2*)(pp + ((size_t)b * 128 + l0 + w * 4 + i) * 1024 + c0 + lane * 2) = r;
    }
}

// in-place softmax over rows of 1024 of (p0+p1+p2+p3); one wave per row
__global__ __launch_bounds__(256) void softmax3(
    float* __restrict__ data, const float* __restrict__ p1,
    const float* __restrict__ p2, const float* __restrict__ p3)
{
    const int row  = blockIdx.x * 4 + (threadIdx.x >> 6);
    const int lane = threadIdx.x & 63;
    float* p = data + (size_t)row * 1024;
    const float* q1 = p1 + (size_t)row * 1024;
    const float* q2 = p2 + (size_t)row * 1024;
    const float* q3 = p3 + (size_t)row * 1024;

    float4 x[4];
#pragma unroll
    for (int j = 0; j < 4; ++j) {
        float4 a = *(const float4*)(p  + j * 256 + lane * 4);
        float4 b = *(const float4*)(q1 + j * 256 + lane * 4);
        float4 c = *(const float4*)(q2 + j * 256 + lane * 4);
        float4 d = *(const float4*)(q3 + j * 256 + lane * 4);
        x[j].x = (a.x + b.x) + (c.x + d.x);
        x[j].y = (a.y + b.y) + (c.y + d.y);
        x[j].z = (a.z + b.z) + (c.z + d.z);
        x[j].w = (a.w + b.w) + (c.w + d.w);
    }

    float m = x[0].x;
#pragma unroll
    for (int j = 0; j < 4; ++j) {
        m = fmaxf(m, x[j].x); m = fmaxf(m, x[j].y);
        m = fmaxf(m, x[j].z); m = fmaxf(m, x[j].w);
    }
#pragma unroll
    for (int mask = 32; mask >= 1; mask >>= 1) m = fmaxf(m, __shfl_xor(m, mask, 64));

    const float LOG2E = 1.4426950408889634f;
    float s = 0.0f;
#pragma unroll
    for (int j = 0; j < 4; ++j) {
        x[j].x = __builtin_amdgcn_exp2f((x[j].x - m) * LOG2E);
        x[j].y = __builtin_amdgcn_exp2f((x[j].y - m) * LOG2E);
        x[j].z = __builtin_amdgcn_exp2f((x[j].z - m) * LOG2E);
        x[j].w = __builtin_amdgcn_exp2f((x[j].w - m) * LOG2E);
        s += x[j].x + x[j].y + x[j].z + x[j].w;
    }
#pragma unroll
    for (int mask = 32; mask >= 1; mask >>= 1) s += __shfl_xor(s, mask, 64);
    const float r = __builtin_amdgcn_rcpf(s);
#pragma unroll
    for (int j = 0; j < 4; ++j) {
        x[j].x *= r; x[j].y *= r; x[j].z *= r; x[j].w *= r;
        *(float4*)(p + j * 256 + lane * 4) = x[j];
    }
}

extern "C" void kernel_launch(void* const* d_in, const int* in_sizes, int n_in,
                              void* d_out, int out_size, void* d_ws, size_t ws_size,
                              hipStream_t stream)
{
    const float* hidden = (const float*)d_in[0];  // [4,128,512]
    const float* ctx    = (const float*)d_in[1];  // [4,1024,512]
    const float* W      = (const float*)d_in[2];  // [512,512]
    const float* U      = (const float*)d_in[3];  // [512,512]
    const float* U_b    = (const float*)d_in[4];  // [512]
    const float* V      = (const float*)d_in[5];  // [512]
    float* out = (float*)d_out;                   // [4,128,1024]

    float* ewq_t = (float*)d_ws;                  // [4][512][128]   (1 MB)
    float* euc_t = ewq_t + 4 * 512 * 128;         // [4][512][1024]  (8 MB)
    float* p1    = euc_t + 4 * 512 * 1024;        // [4][128][1024]  (2 MB)
    float* p2    = p1 + 4 * 128 * 1024;           // (2 MB)
    float* p3    = p2 + 4 * 128 * 1024;           // (2 MB)

    gemm_mfma<<<576, 256, 0, stream>>>(hidden, ctx, W, U, U_b, ewq_t, euc_t);
    fused_align8<<<dim3(8, 8, 16), 256, 0, stream>>>(ewq_t, euc_t, V, out, p1, p2, p3);
    softmax3<<<128, 256, 0, stream>>>(out, p1, p2, p3);
}

// Round 9
// 54.267 us; speedup vs baseline: 3.3382x; 3.3382x over previous
//
#include <hip/hip_runtime.h>
#include <hip/hip_bf16.h>

// B=4, L=128, C=1024, D=512, fp32.
// out[b,l,c] = softmax_c( sum_d V[d]*tanh(wq[b,l,d] + uc[b,c,d]) )
// tanh(x) = 1 - 2/(e^{2x}+1);  e^{2(wq+uc)} = e^{2wq} * e^{2uc};
// shift-invariance drops sum(V):
//   align'[b,l,c] = sum_d (-2 V_d) * rcp(ewq[b,d,l]*euc[b,d,c] + 1)
// Paired over d (1 rcp per 2 elems): V0/t0+V1/t1 = (V0*t1+V1*t0)*rcp(t0*t1).
//
// R9 model (fits align2=30, align7=39, align8=202):
//  - v_rcp_f32 wave64 ~16 cyc (1/8 VALU rate) -> unpaired trans floor 27us,
//    paired 13.6us.
//  - LDS slot costs: b32 5.8 / b64 ~6 / b128 12 cyc per wave-instr.
//  - Register chunk-prefetch arrays kill occupancy (align8: 256 VGPR).
// fused_align9: lane=4 consecutive c (b128 e), wave=4 l (uniform b128 q from
//  LDS), V b64 pairs from LDS. Per d-pair/wave ~54 LDS cyc / 2048 elems.
//  c-tile 256, l-tile 16, d-split 4: grid 512, 35KB LDS, gload16 dbuf.

#define SCALE2 2.8853900817779268f  // 2*log2(e)

typedef _Float16 f16x8 __attribute__((ext_vector_type(8)));
typedef float f32x4 __attribute__((ext_vector_type(4)));

__device__ __forceinline__ void gload16(const void* g, void* l) {
    __builtin_amdgcn_global_load_lds(
        (const __attribute__((address_space(1))) void*)g,
        (__attribute__((address_space(3))) void*)l,
        16, 0, 0);
}

// ---------------------------------------------------------------------------
// GEMM + exp2 via fp16-split MFMA (unchanged since R6, ~16us).
// ---------------------------------------------------------------------------
__global__ __launch_bounds__(256) void gemm_mfma(
    const float* __restrict__ hidden, const float* __restrict__ ctx,
    const float* __restrict__ Wmat, const float* __restrict__ Umat,
    const float* __restrict__ U_b,
    float* __restrict__ ewq_t, float* __restrict__ euc_t)
{
    __shared__ __align__(16) _Float16 Xh[2][64][40];
    __shared__ __align__(16) _Float16 Xl[2][64][40];
    __shared__ __align__(16) _Float16 Wh[2][64][40];
    __shared__ __align__(16) _Float16 Wl[2][64][40];

    const int tid  = threadIdx.x;
    const int lane = tid & 63;
    const int w    = tid >> 6;

    const float *X, *Wm, *bias;
    float* Ct;
    int m0, crow0, Mb, bshift;
    {
        int gb = blockIdx.x;
        if (gb < 64) {
            m0 = (gb & 7) * 64; crow0 = (gb >> 3) * 64;
            X = hidden; Wm = Wmat; bias = nullptr; Ct = ewq_t; Mb = 128; bshift = 7;
        } else {
            int g = gb - 64;
            m0 = (g & 7) * 64; crow0 = (g >> 3) * 64;
            X = ctx; Wm = Umat; bias = U_b; Ct = euc_t; Mb = 1024; bshift = 10;
        }
    }

    const int sr = tid >> 2;
    const int sk = (tid & 3) * 8;
    const float* xsrc = X  + (size_t)(crow0 + sr) * 512 + sk;
    const float* wsrc = Wm + (size_t)(m0    + sr) * 512 + sk;

    f32x4 acc[4];
#pragma unroll
    for (int t = 0; t < 4; ++t) acc[t] = (f32x4){0.f, 0.f, 0.f, 0.f};

    float xr[8], wr[8];
    {
        float4 a = *(const float4*)(xsrc);
        float4 b = *(const float4*)(xsrc + 4);
        float4 c = *(const float4*)(wsrc);
        float4 d = *(const float4*)(wsrc + 4);
        xr[0]=a.x; xr[1]=a.y; xr[2]=a.z; xr[3]=a.w; xr[4]=b.x; xr[5]=b.y; xr[6]=b.z; xr[7]=b.w;
        wr[0]=c.x; wr[1]=c.y; wr[2]=c.z; wr[3]=c.w; wr[4]=d.x; wr[5]=d.y; wr[6]=d.z; wr[7]=d.w;
        f16x8 xh, xl, wh, wl;
#pragma unroll
        for (int i = 0; i < 8; ++i) {
            xh[i] = (_Float16)xr[i]; xl[i] = (_Float16)(xr[i] - (float)xh[i]);
            wh[i] = (_Float16)wr[i]; wl[i] = (_Float16)(wr[i] - (float)wh[i]);
        }
        *(f16x8*)&Xh[0][sr][sk] = xh; *(f16x8*)&Xl[0][sr][sk] = xl;
        *(f16x8*)&Wh[0][sr][sk] = wh; *(f16x8*)&Wl[0][sr][sk] = wl;
    }

    const int fr = lane & 15;
    const int fk = (lane >> 4) * 8;
    const int mrow = w * 16 + fr;

    for (int kc = 0; kc < 16; ++kc) {
        if (kc < 15) {
            float4 a = *(const float4*)(xsrc + (kc + 1) * 32);
            float4 b = *(const float4*)(xsrc + (kc + 1) * 32 + 4);
            float4 c = *(const float4*)(wsrc + (kc + 1) * 32);
            float4 d = *(const float4*)(wsrc + (kc + 1) * 32 + 4);
            xr[0]=a.x; xr[1]=a.y; xr[2]=a.z; xr[3]=a.w; xr[4]=b.x; xr[5]=b.y; xr[6]=b.z; xr[7]=b.w;
            wr[0]=c.x; wr[1]=c.y; wr[2]=c.z; wr[3]=c.w; wr[4]=d.x; wr[5]=d.y; wr[6]=d.z; wr[7]=d.w;
        }
        __syncthreads();
        const int bu = kc & 1;
        const f16x8 ah = *(const f16x8*)&Wh[bu][mrow][fk];
        const f16x8 al = *(const f16x8*)&Wl[bu][mrow][fk];
#pragma unroll
        for (int t = 0; t < 4; ++t) {
            const f16x8 bh = *(const f16x8*)&Xh[bu][t * 16 + fr][fk];
            const f16x8 bl = *(const f16x8*)&Xl[bu][t * 16 + fr][fk];
            acc[t] = __builtin_amdgcn_mfma_f32_16x16x32_f16(ah, bh, acc[t], 0, 0, 0);
            acc[t] = __builtin_amdgcn_mfma_f32_16x16x32_f16(ah, bl, acc[t], 0, 0, 0);
            acc[t] = __builtin_amdgcn_mfma_f32_16x16x32_f16(al, bh, acc[t], 0, 0, 0);
        }
        if (kc < 15) {
            f16x8 xh, xl, wh, wl;
#pragma unroll
            for (int i = 0; i < 8; ++i) {
                xh[i] = (_Float16)xr[i]; xl[i] = (_Float16)(xr[i] - (float)xh[i]);
                wh[i] = (_Float16)wr[i]; wl[i] = (_Float16)(wr[i] - (float)wh[i]);
            }
            *(f16x8*)&Xh[bu ^ 1][sr][sk] = xh; *(f16x8*)&Xl[bu ^ 1][sr][sk] = xl;
            *(f16x8*)&Wh[bu ^ 1][sr][sk] = wh; *(f16x8*)&Wl[bu ^ 1][sr][sk] = wl;
        }
    }

    const int rbase = m0 + w * 16 + (lane >> 4) * 4;
    float bl4[4] = {0.f, 0.f, 0.f, 0.f};
    if (bias) {
        float4 t = *(const float4*)&bias[rbase];
        bl4[0] = t.x; bl4[1] = t.y; bl4[2] = t.z; bl4[3] = t.w;
    }
    const int bidx = crow0 >> bshift;
    const int cl0  = crow0 & (Mb - 1);
    float* obase = Ct + ((size_t)bidx * 512 + rbase) * Mb + cl0 + fr;
#pragma unroll
    for (int r = 0; r < 4; ++r)
#pragma unroll
        for (int t = 0; t < 4; ++t)
            obase[(size_t)r * Mb + t * 16] =
                __builtin_amdgcn_exp2f(SCALE2 * (acc[t][r] + bl4[r]));
}

// ---------------------------------------------------------------------------
// Fused align v9 (paired-rcp, LDS-fed). Block = 256 c x 16 l x 128 d; 4
// waves. Wave w owns l0+w*4..+3; lane owns 4 consecutive c (c0+4*lane..).
// d in 8 chunks of 16, double-buffered via gload16. All hot-loop operands
// from LDS: e b128 per-lane, q b128 uniform, V b64 uniform. acc[4][4].
// Grid (4, 8, 16): z = b*4+h; partial h -> p[h]; softmax3 sums.
// ---------------------------------------------------------------------------
__global__ __launch_bounds__(256) void fused_align9(
    const float* __restrict__ ewq_t,  // [4][512][128]
    const float* __restrict__ euc_t,  // [4][512][1024]
    const float* __restrict__ Vv,     // [512]
    float* __restrict__ p0, float* __restrict__ p1,
    float* __restrict__ p2, float* __restrict__ p3)
{
    __shared__ __align__(16) float uc_s[2][16][256];  // 32 KB
    __shared__ __align__(16) float wq_s[2][16][16];   // 2 KB
    __shared__ __align__(8)  float2 v2_s[64];         // 0.5 KB

    const int tid  = threadIdx.x;
    const int lane = tid & 63;
    const int w    = __builtin_amdgcn_readfirstlane(tid >> 6);
    const int c0   = blockIdx.x * 256;   // 4
    const int l0   = blockIdx.y * 16;    // 8
    const int z    = blockIdx.z;         // 16
    const int b    = z >> 2, h = z & 3;
    const int d0   = h * 128;

    const float* ucb = euc_t + ((size_t)b * 512 + d0) * 1024 + c0;
    const float* wqb = ewq_t + ((size_t)b * 512 + d0) * 128 + l0;

    if (tid < 64)
        v2_s[tid] = make_float2(Vv[d0 + 2 * tid], Vv[d0 + 2 * tid + 1]);

    // Stage one 16-d chunk: uc rows (1 KB each) one gload16 per row, wave w
    // does rows w*4..w*4+3; wq chunk (16x16 = 1 KB) one gload16 by wave 0.
#define STAGE(buf, chunk)                                                     \
    {                                                                         \
        _Pragma("unroll")                                                     \
        for (int i_ = 0; i_ < 4; ++i_) {                                      \
            const int d_ = w * 4 + i_;                                        \
            gload16(ucb + (size_t)((chunk) * 16 + d_) * 1024 + lane * 4,      \
                    &uc_s[buf][d_][0]);                                       \
        }                                                                     \
        if (w == 0)                                                           \
            gload16(wqb + (size_t)((chunk) * 16 + (lane >> 2)) * 128 +        \
                        (lane & 3) * 4,                                       \
                    &wq_s[buf][0][0]);                                        \
    }

    float acc[4][4];
#pragma unroll
    for (int i = 0; i < 4; ++i)
#pragma unroll
        for (int k = 0; k < 4; ++k) acc[i][k] = 0.0f;

    STAGE(0, 0);
    __syncthreads();

    for (int ch = 0; ch < 8; ++ch) {
        if (ch < 7) STAGE((ch + 1) & 1, ch + 1);
        const int bu = ch & 1;
#pragma unroll
        for (int j = 0; j < 8; ++j) {
            const float4 e0 = *(const float4*)&uc_s[bu][2 * j][lane * 4];
            const float4 e1 = *(const float4*)&uc_s[bu][2 * j + 1][lane * 4];
            const float4 q0 = *(const float4*)&wq_s[bu][2 * j][w * 4];
            const float4 q1 = *(const float4*)&wq_s[bu][2 * j + 1][w * 4];
            const float2 vp = v2_s[ch * 8 + j];
            const float q0a[4] = {q0.x, q0.y, q0.z, q0.w};
            const float q1a[4] = {q1.x, q1.y, q1.z, q1.w};
            const float e0a[4] = {e0.x, e0.y, e0.z, e0.w};
            const float e1a[4] = {e1.x, e1.y, e1.z, e1.w};
#pragma unroll
            for (int i = 0; i < 4; ++i) {
#pragma unroll
                for (int k = 0; k < 4; ++k) {
                    const float t0 = fmaf(q0a[i], e0a[k], 1.0f);
                    const float t1 = fmaf(q1a[i], e1a[k], 1.0f);
                    const float n  = fmaf(vp.x, t1, vp.y * t0);
                    acc[i][k] = fmaf(n, __builtin_amdgcn_rcpf(t0 * t1), acc[i][k]);
                }
            }
        }
        __syncthreads();   // drains gload_lds vmcnt + protects buf reuse
    }
#undef STAGE

    float* pp = (h == 0) ? p0 : (h == 1) ? p1 : (h == 2) ? p2 : p3;
#pragma unroll
    for (int i = 0; i < 4; ++i) {
        float4 r;
        r.x = -2.0f * acc[i][0]; r.y = -2.0f * acc[i][1];
        r.z = -2.0f * acc[i][2]; r.w = -2.0f * acc[i][3];
        *(float4*)(pp + ((size_t)b * 128 + l0 + w * 4 + i) * 1024 + c0 + lane * 4) = r;
    }
}

// in-place softmax over rows of 1024 of (p0+p1+p2+p3); one wave per row
__global__ __launch_bounds__(256) void softmax3(
    float* __restrict__ data, const float* __restrict__ p1,
    const float* __restrict__ p2, const float* __restrict__ p3)
{
    const int row  = blockIdx.x * 4 + (threadIdx.x >> 6);
    const int lane = threadIdx.x & 63;
    float* p = data + (size_t)row * 1024;
    const float* q1 = p1 + (size_t)row * 1024;
    const float* q2 = p2 + (size_t)row * 1024;
    const float* q3 = p3 + (size_t)row * 1024;

    float4 x[4];
#pragma unroll
    for (int j = 0; j < 4; ++j) {
        float4 a = *(const float4*)(p  + j * 256 + lane * 4);
        float4 b = *(const float4*)(q1 + j * 256 + lane * 4);
        float4 c = *(const float4*)(q2 + j * 256 + lane * 4);
        float4 d = *(const float4*)(q3 + j * 256 + lane * 4);
        x[j].x = (a.x + b.x) + (c.x + d.x);
        x[j].y = (a.y + b.y) + (c.y + d.y);
        x[j].z = (a.z + b.z) + (c.z + d.z);
        x[j].w = (a.w + b.w) + (c.w + d.w);
    }

    float m = x[0].x;
#pragma unroll
    for (int j = 0; j < 4; ++j) {
        m = fmaxf(m, x[j].x); m = fmaxf(m, x[j].y);
        m = fmaxf(m, x[j].z); m = fmaxf(m, x[j].w);
    }
#pragma unroll
    for (int mask = 32; mask >= 1; mask >>= 1) m = fmaxf(m, __shfl_xor(m, mask, 64));

    const float LOG2E = 1.4426950408889634f;
    float s = 0.0f;
#pragma unroll
    for (int j = 0; j < 4; ++j) {
        x[j].x = __builtin_amdgcn_exp2f((x[j].x - m) * LOG2E);
        x[j].y = __builtin_amdgcn_exp2f((x[j].y - m) * LOG2E);
        x[j].z = __builtin_amdgcn_exp2f((x[j].z - m) * LOG2E);
        x[j].w = __builtin_amdgcn_exp2f((x[j].w - m) * LOG2E);
        s += x[j].x + x[j].y + x[j].z + x[j].w;
    }
#pragma unroll
    for (int mask = 32; mask >= 1; mask >>= 1) s += __shfl_xor(s, mask, 64);
    const float r = __builtin_amdgcn_rcpf(s);
#pragma unroll
    for (int j = 0; j < 4; ++j) {
        x[j].x *= r; x[j].y *= r; x[j].z *= r; x[j].w *= r;
        *(float4*)(p + j * 256 + lane * 4) = x[j];
    }
}

extern "C" void kernel_launch(void* const* d_in, const int* in_sizes, int n_in,
                              void* d_out, int out_size, void* d_ws, size_t ws_size,
                              hipStream_t stream)
{
    const float* hidden = (const float*)d_in[0];  // [4,128,512]
    const float* ctx    = (const float*)d_in[1];  // [4,1024,512]
    const float* W      = (const float*)d_in[2];  // [512,512]
    const float* U      = (const float*)d_in[3];  // [512,512]
    const float* U_b    = (const float*)d_in[4];  // [512]
    const float* V      = (const float*)d_in[5];  // [512]
    float* out = (float*)d_out;                   // [4,128,1024]

    float* ewq_t = (float*)d_ws;                  // [4][512][128]   (1 MB)
    float* euc_t = ewq_t + 4 * 512 * 128;         // [4][512][1024]  (8 MB)
    float* p1    = euc_t + 4 * 512 * 1024;        // [4][128][1024]  (2 MB)
    float* p2    = p1 + 4 * 128 * 1024;           // (2 MB)
    float* p3    = p2 + 4 * 128 * 1024;           // (2 MB)

    gemm_mfma<<<576, 256, 0, stream>>>(hidden, ctx, W, U, U_b, ewq_t, euc_t);
    fused_align9<<<dim3(4, 8, 16), 256, 0, stream>>>(ewq_t, euc_t, V, out, p1, p2, p3);
    softmax3<<<128, 256, 0, stream>>>(out, p1, p2, p3);
}

// Round 10
// 51.810 us; speedup vs baseline: 3.4966x; 1.0474x over previous
//
#include <hip/hip_runtime.h>
#include <hip/hip_bf16.h>

// B=4, L=128, C=1024, D=512, fp32.
// out[b,l,c] = softmax_c( sum_d V[d]*tanh(wq[b,l,d] + uc[b,c,d]) )
// tanh(x) = 1 - 2/(e^{2x}+1); e^{2(wq+uc)} = e^{2wq}*e^{2uc}; shift-invariance
// drops sum(V):  align'[b,l,c] = sum_d (-2 V_d) * rcp(ewq[b,d,l]*euc[b,d,c]+1)
//
// R10: RUNNING-FRACTION accumulation, 1 rcp per 16 d:
//   n/den + V/t = (n*t + V*den)/(den*t):  n=fma(n,t,V*den); den*=t  (3 VALU)
//   + t=fma(q,e,1) (1 VALU). acc += n*rcp(den) once per 16-d group.
// Issue model (fits align7=39, align9=34): v_rcp_f32 blocks issue 16 cyc;
// VALU 2 cyc; cost = 0.15 cyc/elem -> 15.4us/SIMD; LDS ~16.6us/CU.
// Overflow: den = prod(1+e^x) <= e^66 max over data (x~N(0,2.83)) << fp32 max.
// Geometry: c-tile 256 (4c/lane b128), l-tile 16 (4l/wave uniform b128),
// d-tile 64 (4 chunks of 16, gload16 double-buffered, 5 barriers).
// Grid (4,8,32) = 1024 blocks = 4/CU. 8 d-partials; softmax4 sums.

#define SCALE2 2.8853900817779268f  // 2*log2(e)
#define PART (4 * 128 * 1024)

typedef _Float16 f16x8 __attribute__((ext_vector_type(8)));
typedef float f32x4 __attribute__((ext_vector_type(4)));

__device__ __forceinline__ void gload16(const void* g, void* l) {
    __builtin_amdgcn_global_load_lds(
        (const __attribute__((address_space(1))) void*)g,
        (__attribute__((address_space(3))) void*)l,
        16, 0, 0);
}

// ---------------------------------------------------------------------------
// GEMM + exp2 via fp16-split MFMA (unchanged since R6, ~16us).
// ---------------------------------------------------------------------------
__global__ __launch_bounds__(256) void gemm_mfma(
    const float* __restrict__ hidden, const float* __restrict__ ctx,
    const float* __restrict__ Wmat, const float* __restrict__ Umat,
    const float* __restrict__ U_b,
    float* __restrict__ ewq_t, float* __restrict__ euc_t)
{
    __shared__ __align__(16) _Float16 Xh[2][64][40];
    __shared__ __align__(16) _Float16 Xl[2][64][40];
    __shared__ __align__(16) _Float16 Wh[2][64][40];
    __shared__ __align__(16) _Float16 Wl[2][64][40];

    const int tid  = threadIdx.x;
    const int lane = tid & 63;
    const int w    = tid >> 6;

    const float *X, *Wm, *bias;
    float* Ct;
    int m0, crow0, Mb, bshift;
    {
        int gb = blockIdx.x;
        if (gb < 64) {
            m0 = (gb & 7) * 64; crow0 = (gb >> 3) * 64;
            X = hidden; Wm = Wmat; bias = nullptr; Ct = ewq_t; Mb = 128; bshift = 7;
        } else {
            int g = gb - 64;
            m0 = (g & 7) * 64; crow0 = (g >> 3) * 64;
            X = ctx; Wm = Umat; bias = U_b; Ct = euc_t; Mb = 1024; bshift = 10;
        }
    }

    const int sr = tid >> 2;
    const int sk = (tid & 3) * 8;
    const float* xsrc = X  + (size_t)(crow0 + sr) * 512 + sk;
    const float* wsrc = Wm + (size_t)(m0    + sr) * 512 + sk;

    f32x4 acc[4];
#pragma unroll
    for (int t = 0; t < 4; ++t) acc[t] = (f32x4){0.f, 0.f, 0.f, 0.f};

    float xr[8], wr[8];
    {
        float4 a = *(const float4*)(xsrc);
        float4 b = *(const float4*)(xsrc + 4);
        float4 c = *(const float4*)(wsrc);
        float4 d = *(const float4*)(wsrc + 4);
        xr[0]=a.x; xr[1]=a.y; xr[2]=a.z; xr[3]=a.w; xr[4]=b.x; xr[5]=b.y; xr[6]=b.z; xr[7]=b.w;
        wr[0]=c.x; wr[1]=c.y; wr[2]=c.z; wr[3]=c.w; wr[4]=d.x; wr[5]=d.y; wr[6]=d.z; wr[7]=d.w;
        f16x8 xh, xl, wh, wl;
#pragma unroll
        for (int i = 0; i < 8; ++i) {
            xh[i] = (_Float16)xr[i]; xl[i] = (_Float16)(xr[i] - (float)xh[i]);
            wh[i] = (_Float16)wr[i]; wl[i] = (_Float16)(wr[i] - (float)wh[i]);
        }
        *(f16x8*)&Xh[0][sr][sk] = xh; *(f16x8*)&Xl[0][sr][sk] = xl;
        *(f16x8*)&Wh[0][sr][sk] = wh; *(f16x8*)&Wl[0][sr][sk] = wl;
    }

    const int fr = lane & 15;
    const int fk = (lane >> 4) * 8;
    const int mrow = w * 16 + fr;

    for (int kc = 0; kc < 16; ++kc) {
        if (kc < 15) {
            float4 a = *(const float4*)(xsrc + (kc + 1) * 32);
            float4 b = *(const float4*)(xsrc + (kc + 1) * 32 + 4);
            float4 c = *(const float4*)(wsrc + (kc + 1) * 32);
            float4 d = *(const float4*)(wsrc + (kc + 1) * 32 + 4);
            xr[0]=a.x; xr[1]=a.y; xr[2]=a.z; xr[3]=a.w; xr[4]=b.x; xr[5]=b.y; xr[6]=b.z; xr[7]=b.w;
            wr[0]=c.x; wr[1]=c.y; wr[2]=c.z; wr[3]=c.w; wr[4]=d.x; wr[5]=d.y; wr[6]=d.z; wr[7]=d.w;
        }
        __syncthreads();
        const int bu = kc & 1;
        const f16x8 ah = *(const f16x8*)&Wh[bu][mrow][fk];
        const f16x8 al = *(const f16x8*)&Wl[bu][mrow][fk];
#pragma unroll
        for (int t = 0; t < 4; ++t) {
            const f16x8 bh = *(const f16x8*)&Xh[bu][t * 16 + fr][fk];
            const f16x8 bl = *(const f16x8*)&Xl[bu][t * 16 + fr][fk];
            acc[t] = __builtin_amdgcn_mfma_f32_16x16x32_f16(ah, bh, acc[t], 0, 0, 0);
            acc[t] = __builtin_amdgcn_mfma_f32_16x16x32_f16(ah, bl, acc[t], 0, 0, 0);
            acc[t] = __builtin_amdgcn_mfma_f32_16x16x32_f16(al, bh, acc[t], 0, 0, 0);
        }
        if (kc < 15) {
            f16x8 xh, xl, wh, wl;
#pragma unroll
            for (int i = 0; i < 8; ++i) {
                xh[i] = (_Float16)xr[i]; xl[i] = (_Float16)(xr[i] - (float)xh[i]);
                wh[i] = (_Float16)wr[i]; wl[i] = (_Float16)(wr[i] - (float)wh[i]);
            }
            *(f16x8*)&Xh[bu ^ 1][sr][sk] = xh; *(f16x8*)&Xl[bu ^ 1][sr][sk] = xl;
            *(f16x8*)&Wh[bu ^ 1][sr][sk] = wh; *(f16x8*)&Wl[bu ^ 1][sr][sk] = wl;
        }
    }

    const int rbase = m0 + w * 16 + (lane >> 4) * 4;
    float bl4[4] = {0.f, 0.f, 0.f, 0.f};
    if (bias) {
        float4 t = *(const float4*)&bias[rbase];
        bl4[0] = t.x; bl4[1] = t.y; bl4[2] = t.z; bl4[3] = t.w;
    }
    const int bidx = crow0 >> bshift;
    const int cl0  = crow0 & (Mb - 1);
    float* obase = Ct + ((size_t)bidx * 512 + rbase) * Mb + cl0 + fr;
#pragma unroll
    for (int r = 0; r < 4; ++r)
#pragma unroll
        for (int t = 0; t < 4; ++t)
            obase[(size_t)r * Mb + t * 16] =
                __builtin_amdgcn_exp2f(SCALE2 * (acc[t][r] + bl4[r]));
}

// ---------------------------------------------------------------------------
// Fused align v10: running-fraction, 1 rcp / 16 d. Block = 256c x 16l x 64d;
// 4 waves; wave w owns l0+w*4..+3; lane owns c0+4*lane..+3.
// 4 chunks of 16 d, gload16 double-buffered, static buffer indexing.
// Grid (4,8,32): z = b*8+h; partial h=0 -> pout, else pws[h-1].
// ---------------------------------------------------------------------------
__global__ __launch_bounds__(256) void fused_align10(
    const float* __restrict__ ewq_t,  // [4][512][128]
    const float* __restrict__ euc_t,  // [4][512][1024]
    const float* __restrict__ Vv,     // [512]
    float* __restrict__ pout, float* __restrict__ pws)
{
    __shared__ __align__(16) float uc_s[2][16][256];  // 32 KB
    __shared__ __align__(16) float wq_s[2][16][16];   // 2 KB
    __shared__ float v_s[64];

    const int tid  = threadIdx.x;
    const int lane = tid & 63;
    const int w    = __builtin_amdgcn_readfirstlane(tid >> 6);
    const int c0   = blockIdx.x * 256;   // 4
    const int l0   = blockIdx.y * 16;    // 8
    const int z    = blockIdx.z;         // 32
    const int b    = z >> 3, h = z & 7;
    const int d0   = h * 64;

    const float* ucb = euc_t + ((size_t)b * 512 + d0) * 1024 + c0;
    const float* wqb = ewq_t + ((size_t)b * 512 + d0) * 128 + l0;

    if (tid < 64) v_s[tid] = Vv[d0 + tid];

#define STAGE(buf, chunk)                                                     \
    {                                                                         \
        _Pragma("unroll")                                                     \
        for (int i_ = 0; i_ < 4; ++i_) {                                      \
            const int d_ = w * 4 + i_;                                        \
            gload16(ucb + (size_t)((chunk) * 16 + d_) * 1024 + lane * 4,      \
                    &uc_s[buf][d_][0]);                                       \
        }                                                                     \
        if (w == 0)                                                           \
            gload16(wqb + (size_t)((chunk) * 16 + (lane >> 2)) * 128 +        \
                        (lane & 3) * 4,                                       \
                    &wq_s[buf][0][0]);                                        \
    }

    float acc[4][4];
#pragma unroll
    for (int i = 0; i < 4; ++i)
#pragma unroll
        for (int k = 0; k < 4; ++k) acc[i][k] = 0.0f;

#define COMPUTE(bu, ch)                                                       \
    do {                                                                      \
        float vr[16];                                                         \
        _Pragma("unroll")                                                     \
        for (int j_ = 0; j_ < 4; ++j_) {                                      \
            const float4 v4_ = *(const float4*)&v_s[(ch) * 16 + j_ * 4];      \
            vr[j_ * 4 + 0] = v4_.x; vr[j_ * 4 + 1] = v4_.y;                   \
            vr[j_ * 4 + 2] = v4_.z; vr[j_ * 4 + 3] = v4_.w;                   \
        }                                                                     \
        float nn[4][4], dn[4][4];                                             \
        {                                                                     \
            const float4 e = *(const float4*)&uc_s[bu][0][lane * 4];          \
            const float4 q = *(const float4*)&wq_s[bu][0][w * 4];             \
            const float ea[4] = {e.x, e.y, e.z, e.w};                         \
            const float qa[4] = {q.x, q.y, q.z, q.w};                         \
            _Pragma("unroll")                                                 \
            for (int i = 0; i < 4; ++i)                                       \
                _Pragma("unroll")                                             \
                for (int k = 0; k < 4; ++k) {                                 \
                    dn[i][k] = fmaf(qa[i], ea[k], 1.0f);                      \
                    nn[i][k] = vr[0];                                         \
                }                                                             \
        }                                                                     \
        _Pragma("unroll")                                                     \
        for (int dd = 1; dd < 16; ++dd) {                                     \
            const float4 e = *(const float4*)&uc_s[bu][dd][lane * 4];         \
            const float4 q = *(const float4*)&wq_s[bu][dd][w * 4];            \
            const float ea[4] = {e.x, e.y, e.z, e.w};                         \
            const float qa[4] = {q.x, q.y, q.z, q.w};                         \
            const float vv = vr[dd];                                          \
            _Pragma("unroll")                                                 \
            for (int i = 0; i < 4; ++i)                                       \
                _Pragma("unroll")                                             \
                for (int k = 0; k < 4; ++k) {                                 \
                    const float t_ = fmaf(qa[i], ea[k], 1.0f);                \
                    nn[i][k] = fmaf(nn[i][k], t_, vv * dn[i][k]);             \
                    dn[i][k] *= t_;                                           \
                }                                                             \
        }                                                                     \
        _Pragma("unroll")                                                     \
        for (int i = 0; i < 4; ++i)                                           \
            _Pragma("unroll")                                                 \
            for (int k = 0; k < 4; ++k)                                       \
                acc[i][k] = fmaf(nn[i][k],                                    \
                                 __builtin_amdgcn_rcpf(dn[i][k]), acc[i][k]); \
    } while (0)

    STAGE(0, 0);
    __syncthreads();

    for (int cc = 0; cc < 2; ++cc) {
        STAGE(1, 2 * cc + 1);
        COMPUTE(0, 2 * cc);
        __syncthreads();
        if (cc == 0) STAGE(0, 2);
        COMPUTE(1, 2 * cc + 1);
        __syncthreads();
    }
#undef STAGE
#undef COMPUTE

    float* pp = (h == 0) ? pout : pws + (size_t)(h - 1) * PART;
#pragma unroll
    for (int i = 0; i < 4; ++i) {
        float4 r;
        r.x = -2.0f * acc[i][0]; r.y = -2.0f * acc[i][1];
        r.z = -2.0f * acc[i][2]; r.w = -2.0f * acc[i][3];
        *(float4*)(pp + ((size_t)b * 128 + l0 + w * 4 + i) * 1024 + c0 + lane * 4) = r;
    }
}

// in-place softmax over rows of 1024 of (data + 7 ws partials); 1 wave/row
__global__ __launch_bounds__(256) void softmax4(
    float* __restrict__ data, const float* __restrict__ pws)
{
    const int row  = blockIdx.x * 4 + (threadIdx.x >> 6);
    const int lane = threadIdx.x & 63;
    float* p = data + (size_t)row * 1024;

    float4 x[4];
#pragma unroll
    for (int j = 0; j < 4; ++j) x[j] = *(const float4*)(p + j * 256 + lane * 4);
#pragma unroll
    for (int t = 0; t < 7; ++t) {
        const float* q = pws + (size_t)t * PART + (size_t)row * 1024;
#pragma unroll
        for (int j = 0; j < 4; ++j) {
            const float4 a = *(const float4*)(q + j * 256 + lane * 4);
            x[j].x += a.x; x[j].y += a.y; x[j].z += a.z; x[j].w += a.w;
        }
    }

    float m = x[0].x;
#pragma unroll
    for (int j = 0; j < 4; ++j) {
        m = fmaxf(m, x[j].x); m = fmaxf(m, x[j].y);
        m = fmaxf(m, x[j].z); m = fmaxf(m, x[j].w);
    }
#pragma unroll
    for (int mask = 32; mask >= 1; mask >>= 1) m = fmaxf(m, __shfl_xor(m, mask, 64));

    const float LOG2E = 1.4426950408889634f;
    float s = 0.0f;
#pragma unroll
    for (int j = 0; j < 4; ++j) {
        x[j].x = __builtin_amdgcn_exp2f((x[j].x - m) * LOG2E);
        x[j].y = __builtin_amdgcn_exp2f((x[j].y - m) * LOG2E);
        x[j].z = __builtin_amdgcn_exp2f((x[j].z - m) * LOG2E);
        x[j].w = __builtin_amdgcn_exp2f((x[j].w - m) * LOG2E);
        s += x[j].x + x[j].y + x[j].z + x[j].w;
    }
#pragma unroll
    for (int mask = 32; mask >= 1; mask >>= 1) s += __shfl_xor(s, mask, 64);
    const float r = __builtin_amdgcn_rcpf(s);
#pragma unroll
    for (int j = 0; j < 4; ++j) {
        x[j].x *= r; x[j].y *= r; x[j].z *= r; x[j].w *= r;
        *(float4*)(p + j * 256 + lane * 4) = x[j];
    }
}

extern "C" void kernel_launch(void* const* d_in, const int* in_sizes, int n_in,
                              void* d_out, int out_size, void* d_ws, size_t ws_size,
                              hipStream_t stream)
{
    const float* hidden = (const float*)d_in[0];  // [4,128,512]
    const float* ctx    = (const float*)d_in[1];  // [4,1024,512]
    const float* W      = (const float*)d_in[2];  // [512,512]
    const float* U      = (const float*)d_in[3];  // [512,512]
    const float* U_b    = (const float*)d_in[4];  // [512]
    const float* V      = (const float*)d_in[5];  // [512]
    float* out = (float*)d_out;                   // [4,128,1024]

    float* ewq_t = (float*)d_ws;                  // [4][512][128]   (1 MB)
    float* euc_t = ewq_t + 4 * 512 * 128;         // [4][512][1024]  (8 MB)
    float* pws   = euc_t + 4 * 512 * 1024;        // 7 x [4][128][1024] (14 MB)

    gemm_mfma<<<576, 256, 0, stream>>>(hidden, ctx, W, U, U_b, ewq_t, euc_t);
    fused_align10<<<dim3(4, 8, 32), 256, 0, stream>>>(ewq_t, euc_t, V, out, pws);
    softmax4<<<128, 256, 0, stream>>>(out, pws);
}